// Round 6
// baseline (892.681 us; speedup 1.0000x reference)
//
#include <hip/hip_runtime.h>
#include <hip/hip_fp16.h>

typedef unsigned int u32;

// 20-qubit state-vector sim, batch 8. Inter-pass state stored FP16 (16 MB total,
// 2 MB per XCD slice -> resident in 4 MB per-XCD L2); gate math fp32.
// qubit q <-> bit (19-q). RY: new0 = c*a + s*b ; new1 = c*b - s*a.
// Chain per layer (bits): (19->18)...(1->0),(0->19) (wrap deferred to next hi phase).
// Hi phase: resident {19..11}u{3..0}, tile m = b10..b4. Lo phase: resident {12..0},
// tile m = b19..b13. ONE cooperative kernel, 1024 blocks (4/CU), 26 phases.
//
// Barrier design (round-6 fix): NO atomic RMW in the hot path. Arrival = relaxed
// agent store of phase number u into the block's own slot; wait = wave0 polls the
// slice's 128 slots (64 lanes x 2 loads + __all). Slice s = blk&7 verified against
// physical XCC_ID at startup (one strong global flag barrier while L2 is clean);
// mismatch -> 'bad' -> same schedule with agent release/acquire fences (correct
// under any block->XCD mapping). Weak barriers: stores drained to local L2 by
// __syncthreads (vmcnt0) before arrival; vL1 buffer_inv after release.

#define LDSN 2048  // float4 entries = 32 KB

__device__ __forceinline__ int swzH(int l) { return l ^ (((l >> 5) & 1) << 2); }
__device__ __forceinline__ int swzL(int l) { return l ^ ((l >> 3) & 7); }

__device__ __forceinline__ void h4_to_f(uint2 q, float* d) {
  float2 a = __half22float2(*(__half2*)&q.x);
  float2 b = __half22float2(*(__half2*)&q.y);
  d[0] = a.x; d[1] = a.y; d[2] = b.x; d[3] = b.y;
}
__device__ __forceinline__ uint2 f4_to_h(const float* s) {
  __half2 a = __float22half2_rn(make_float2(s[0], s[1]));
  __half2 b = __float22half2_rn(make_float2(s[2], s[3]));
  uint2 q; q.x = *(u32*)&a; q.y = *(u32*)&b; return q;
}

template<int K>
__device__ __forceinline__ void ry32(float* v, float c, float s) {
#pragma unroll
  for (int i = 0; i < 32; ++i)
    if (!(i & (1 << K))) {
      float a = v[i], b = v[i | (1 << K)];
      v[i] = c * a + s * b;
      v[i | (1 << K)] = c * b - s * a;
    }
}
template<int J, int K>
__device__ __forceinline__ void cnot_rr32(float* v) {
#pragma unroll
  for (int i = 0; i < 32; ++i)
    if ((i & (1 << J)) && !(i & (1 << K))) {
      float tmp = v[i]; v[i] = v[i | (1 << K)]; v[i | (1 << K)] = tmp;
    }
}
template<int K>
__device__ __forceinline__ void cnot_tr32(float* v, int cond) {
#pragma unroll
  for (int i = 0; i < 32; ++i)
    if (!(i & (1 << K))) {
      float a = v[i], b = v[i | (1 << K)];
      v[i] = cond ? b : a;
      v[i | (1 << K)] = cond ? a : b;
    }
}

// ---------------- Hi phase body ----------------
// R1: reg {19,18,17,1,0}; thread t7..t2 = b16..b11, t1t0 = b3b2
// R2: reg {16,15,14,1,0}; thread t7..t5 = b19..b17, t4..t2 = b13..b11, t1t0 = b3b2
// R3: reg {13,12,11,1,0}; thread t7..t2 = b19..b14, t1t0 = b3b2
__device__ __forceinline__ void phase_hi(const void* __restrict__ src, int srcf32,
                                         uint2* __restrict__ dst, const float2* csl,
                                         int s, int m, int do_wrap, int do_chain, float4* lds4) {
  const int t = threadIdx.x;
  const size_t sbase = ((size_t)s << 18) | ((size_t)m << 2);
  float v[32];

  if (srcf32) {
    const float4* s4 = (const float4*)src;
#pragma unroll
    for (int rq = 0; rq < 8; ++rq) {
      size_t g4 = sbase | ((size_t)rq << 15) | ((size_t)(t >> 2) << 9) | (size_t)(t & 3);
      float4 x = s4[g4];
      v[4*rq] = x.x; v[4*rq+1] = x.y; v[4*rq+2] = x.z; v[4*rq+3] = x.w;
    }
  } else {
    const uint2* sh = (const uint2*)src;
#pragma unroll
    for (int rq = 0; rq < 8; ++rq) {
      size_t g4 = sbase | ((size_t)rq << 15) | ((size_t)(t >> 2) << 9) | (size_t)(t & 3);
      h4_to_f(sh[g4], &v[4*rq]);
    }
  }
  if (do_wrap) cnot_rr32<0, 4>(v);                 // wrap (0->19) of previous layer
  { float2 a = csl[0]; ry32<4>(v, a.x, a.y); }     // q0  b19
  { float2 a = csl[1]; ry32<3>(v, a.x, a.y); }     // q1  b18
  { float2 a = csl[2]; ry32<2>(v, a.x, a.y); }     // q2  b17
  if (do_chain) { cnot_rr32<4, 3>(v); cnot_rr32<3, 2>(v); }  // (19->18),(18->17)
#pragma unroll
  for (int rq = 0; rq < 8; ++rq)
    lds4[swzH((rq << 8) | t)] = make_float4(v[4*rq], v[4*rq+1], v[4*rq+2], v[4*rq+3]);
  __syncthreads();
#pragma unroll
  for (int rq = 0; rq < 8; ++rq) {
    int l = ((t >> 5) << 8) | (rq << 5) | (((t >> 2) & 7) << 2) | (t & 3);
    float4 x = lds4[swzH(l)];
    v[4*rq] = x.x; v[4*rq+1] = x.y; v[4*rq+2] = x.z; v[4*rq+3] = x.w;
  }
  { float2 a = csl[3]; ry32<4>(v, a.x, a.y); }     // q3  b16
  { float2 a = csl[4]; ry32<3>(v, a.x, a.y); }     // q4  b15
  { float2 a = csl[5]; ry32<2>(v, a.x, a.y); }     // q5  b14
  if (do_chain) {
    cnot_tr32<4>(v, (t >> 5) & 1);                 // (17->16), ctrl b17 = t5
    cnot_rr32<4, 3>(v);                            // (16->15)
    cnot_rr32<3, 2>(v);                            // (15->14)
  }
#pragma unroll
  for (int rq = 0; rq < 8; ++rq) {
    int l = ((t >> 5) << 8) | (rq << 5) | (((t >> 2) & 7) << 2) | (t & 3);
    lds4[swzH(l)] = make_float4(v[4*rq], v[4*rq+1], v[4*rq+2], v[4*rq+3]);
  }
  __syncthreads();
#pragma unroll
  for (int rq = 0; rq < 8; ++rq) {
    int l = ((t >> 2) << 5) | (rq << 2) | (t & 3);
    float4 x = lds4[swzH(l)];
    v[4*rq] = x.x; v[4*rq+1] = x.y; v[4*rq+2] = x.z; v[4*rq+3] = x.w;
  }
  { float2 a = csl[6]; ry32<4>(v, a.x, a.y); }     // q6  b13
  { float2 a = csl[7]; ry32<3>(v, a.x, a.y); }     // q7  b12
  { float2 a = csl[8]; ry32<2>(v, a.x, a.y); }     // q8  b11
  if (do_chain) {
    cnot_tr32<4>(v, (t >> 2) & 1);                 // (14->13), ctrl b14 = t2
    cnot_rr32<4, 3>(v);                            // (13->12)
    cnot_rr32<3, 2>(v);                            // (12->11)
  }
#pragma unroll
  for (int rq = 0; rq < 8; ++rq) {
    size_t g4 = sbase | ((size_t)(t >> 2) << 12) | ((size_t)rq << 9) | (size_t)(t & 3);
    dst[g4] = f4_to_h(&v[4*rq]);
  }
}

// ---------------- Lo phase body ----------------
// R1: reg {10,9,8,1,0};  thread t7t6 = b12b11, t5..t0 = b7..b2
// R2: reg {7,6,5,1,0};   thread t7..t3 = b12..b8, t2..t0 = b4..b2
// R3: reg {4,3,2,1,0};   thread t7..t0 = b12..b5
__device__ __forceinline__ void phase_lo(const uint2* __restrict__ src, uint2* __restrict__ dst,
                                         const float2* csl, int s, int m,
                                         int do_chain, int do_meas, float* outp, float4* lds4) {
  const int t = threadIdx.x;
  const size_t base4 = ((size_t)s << 18) | ((size_t)m << 11);
  float v[32];

#pragma unroll
  for (int rq = 0; rq < 8; ++rq) {
    int l = ((t >> 6) << 9) | (rq << 6) | (t & 63);
    h4_to_f(src[base4 + l], &v[4*rq]);
  }
  { float2 a = csl[9];  ry32<4>(v, a.x, a.y); }    // q9  b10
  { float2 a = csl[10]; ry32<3>(v, a.x, a.y); }    // q10 b9
  { float2 a = csl[11]; ry32<2>(v, a.x, a.y); }    // q11 b8
  if (do_chain) {
    cnot_tr32<4>(v, (t >> 6) & 1);                 // (11->10), ctrl b11 = t6
    cnot_rr32<4, 3>(v);                            // (10->9)
    cnot_rr32<3, 2>(v);                            // (9->8)
  }
#pragma unroll
  for (int rq = 0; rq < 8; ++rq) {
    int l = ((t >> 6) << 9) | (rq << 6) | (t & 63);
    lds4[swzL(l)] = make_float4(v[4*rq], v[4*rq+1], v[4*rq+2], v[4*rq+3]);
  }
  __syncthreads();
#pragma unroll
  for (int rq = 0; rq < 8; ++rq) {
    int l = ((t >> 3) << 6) | (rq << 3) | (t & 7);
    float4 x = lds4[swzL(l)];
    v[4*rq] = x.x; v[4*rq+1] = x.y; v[4*rq+2] = x.z; v[4*rq+3] = x.w;
  }
  { float2 a = csl[12]; ry32<4>(v, a.x, a.y); }    // q12 b7
  { float2 a = csl[13]; ry32<3>(v, a.x, a.y); }    // q13 b6
  { float2 a = csl[14]; ry32<2>(v, a.x, a.y); }    // q14 b5
  if (do_chain) {
    cnot_tr32<4>(v, (t >> 3) & 1);                 // (8->7), ctrl b8 = t3
    cnot_rr32<4, 3>(v);                            // (7->6)
    cnot_rr32<3, 2>(v);                            // (6->5)
  }
#pragma unroll
  for (int rq = 0; rq < 8; ++rq) {
    int l = ((t >> 3) << 6) | (rq << 3) | (t & 7);
    lds4[swzL(l)] = make_float4(v[4*rq], v[4*rq+1], v[4*rq+2], v[4*rq+3]);
  }
  __syncthreads();
#pragma unroll
  for (int rq = 0; rq < 8; ++rq) {
    int l = (t << 3) | rq;
    float4 x = lds4[swzL(l)];
    v[4*rq] = x.x; v[4*rq+1] = x.y; v[4*rq+2] = x.z; v[4*rq+3] = x.w;
  }
  { float2 a = csl[15]; ry32<4>(v, a.x, a.y); }    // q15 b4
  { float2 a = csl[16]; ry32<3>(v, a.x, a.y); }    // q16 b3
  { float2 a = csl[17]; ry32<2>(v, a.x, a.y); }    // q17 b2
  { float2 a = csl[18]; ry32<1>(v, a.x, a.y); }    // q18 b1
  { float2 a = csl[19]; ry32<0>(v, a.x, a.y); }    // q19 b0
  if (do_chain) {
    cnot_tr32<4>(v, t & 1);                        // (5->4), ctrl b5 = t0
    cnot_rr32<4, 3>(v);                            // (4->3)
    cnot_rr32<3, 2>(v);                            // (3->2)
    cnot_rr32<2, 1>(v);                            // (2->1)
    cnot_rr32<1, 0>(v);                            // (1->0)
  }

  if (!do_meas) {
#pragma unroll
    for (int rq = 0; rq < 8; ++rq) {
      int l = (t << 3) | rq;
      lds4[swzL(l)] = make_float4(v[4*rq], v[4*rq+1], v[4*rq+2], v[4*rq+3]);
    }
    __syncthreads();
#pragma unroll
    for (int rq = 0; rq < 8; ++rq) {
      int l = ((t >> 6) << 9) | (rq << 6) | (t & 63);
      float4 x = lds4[swzL(l)];
      dst[base4 + l] = f4_to_h((float*)&x);
    }
  } else {
    float p[8];
#pragma unroll
    for (int b = 0; b < 8; ++b) p[b] = 0.f;
#pragma unroll
    for (int rq = 0; rq < 8; ++rq)
#pragma unroll
      for (int j = 0; j < 4; ++j) {
        float a = v[4*rq + j];
        p[((rq & 1) << 2) | j] += a * a;
      }
#pragma unroll
    for (int b = 0; b < 8; ++b) {
      p[b] += __shfl_xor(p[b], 32);
      p[b] += __shfl_xor(p[b], 16);
      p[b] += __shfl_xor(p[b], 8);
      p[b] += __shfl_xor(p[b], 4);
      p[b] += __shfl_xor(p[b], 2);
      p[b] += __shfl_xor(p[b], 1);
    }
    __syncthreads();
    float* red = (float*)lds4;
    if ((t & 63) == 0) {
#pragma unroll
      for (int b = 0; b < 8; ++b) red[(t >> 6) * 8 + b] = p[b];
    }
    __syncthreads();
    if (t < 8) {
      float sum = red[t] + red[8 + t] + red[16 + t] + red[24 + t];
      atomicAdd(outp + s * 8 + t, sum);
    }
  }
}

// ---------------- flag-array slice barrier (no RMW) ----------------
// Arrival: relaxed agent store of monotonic phase number u into own slot.
// Wait: wave0 polls the slice's 128 slots; done when min >= u.
// weak: stores already in local L2 (vmcnt0 at __syncthreads); vL1 inv after.
// strong: agent release/acquire fences -> correct under any block->XCD mapping.
__device__ __forceinline__ void barx(int* myflag, const int* xf, int u, bool strong) {
  __syncthreads();
  if (strong) __builtin_amdgcn_fence(__ATOMIC_RELEASE, "agent");
  if (threadIdx.x == 0)
    __hip_atomic_store(myflag, u, __ATOMIC_RELAXED, __HIP_MEMORY_SCOPE_AGENT);
  if (threadIdx.x < 64) {
    const int i2 = threadIdx.x * 2;
    for (;;) {
      int a = __hip_atomic_load(xf + i2,     __ATOMIC_RELAXED, __HIP_MEMORY_SCOPE_AGENT);
      int b = __hip_atomic_load(xf + i2 + 1, __ATOMIC_RELAXED, __HIP_MEMORY_SCOPE_AGENT);
      if (__all((a < b ? a : b) >= u)) break;
      __builtin_amdgcn_s_sleep(4);
    }
  }
  __syncthreads();
  if (strong) __builtin_amdgcn_fence(__ATOMIC_ACQUIRE, "agent");
  else asm volatile("buffer_inv" ::: "memory");  // invalidate this CU's vL1
}

// bar layout (ints): [0] bad flag; [64..1087] startup flags (1024);
// [1280..2303] phase flags (8 slices x 128).
__global__ __launch_bounds__(256, 4)
void qae_mega(const float* __restrict__ x, const float* __restrict__ theta,
              uint2* __restrict__ state, float* __restrict__ outp, int* __restrict__ bar) {
  __shared__ float4 lds4[LDSN];
  __shared__ float2 csh[260];
  __shared__ int sh_bad;
  const int t = threadIdx.x;
  const int blk = blockIdx.x;
  const int s = blk & 7;
  const int m = blk >> 3;

  for (int i = t; i < 260; i += 256) {
    float h = 0.5f * theta[i];
    csh[i] = make_float2(cosf(h), sinf(h));
  }
  // verify physical XCD == blk&7 (HW_REG_XCC_ID: id 20, offset 0, width 32)
  if (t == 0) {
    int xcd = __builtin_amdgcn_s_getreg(20 | (31 << 11)) & 7;
    if (xcd != s)
      __hip_atomic_store(bar, 1, __ATOMIC_RELAXED, __HIP_MEMORY_SCOPE_AGENT);
  }
  // startup strong global flag barrier (publishes bad; L2 clean -> fences cheap)
  __syncthreads();
  __builtin_amdgcn_fence(__ATOMIC_RELEASE, "agent");
  if (t == 0)
    __hip_atomic_store(bar + 64 + blk, 1, __ATOMIC_RELAXED, __HIP_MEMORY_SCOPE_AGENT);
  if (t < 64) {
    const int* f = bar + 64 + t * 16;
    for (;;) {
      int mn = 1 << 30;
#pragma unroll
      for (int j = 0; j < 16; ++j) {
        int vv = __hip_atomic_load(f + j, __ATOMIC_RELAXED, __HIP_MEMORY_SCOPE_AGENT);
        mn = (vv < mn) ? vv : mn;
      }
      if (__all(mn >= 1)) break;
      __builtin_amdgcn_s_sleep(8);
    }
  }
  __syncthreads();
  __builtin_amdgcn_fence(__ATOMIC_ACQUIRE, "agent");
  if (t == 0)
    sh_bad = __hip_atomic_load(bar, __ATOMIC_RELAXED, __HIP_MEMORY_SCOPE_AGENT);
  __syncthreads();
  const bool strong = (sh_bad != 0);
  int* myflag = bar + 1280 + s * 128 + m;
  const int* xflags = bar + 1280 + s * 128;
  int u = 0;

#pragma unroll 1
  for (int L = 0; L < 13; ++L) {
    phase_hi((L == 0) ? (const void*)x : (const void*)state, (L == 0) ? 1 : 0,
             state, csh + L * 20, s, m, (L >= 1) ? 1 : 0, (L < 12) ? 1 : 0, lds4);
    barx(myflag, xflags, ++u, strong);
    phase_lo(state, state, csh + L * 20, s, m,
             (L < 12) ? 1 : 0, (L == 12) ? 1 : 0, outp, lds4);
    if (L < 12) barx(myflag, xflags, ++u, strong);
  }
}

// ---------------- standalone fallback kernels (multi-dispatch path) ----------------
__global__ void prep_angles(const float* __restrict__ theta, float2* __restrict__ cs) {
  int i = threadIdx.x;
  if (i < 260) {
    float h = 0.5f * theta[i];
    cs[i] = make_float2(cosf(h), sinf(h));
  }
}

__global__ __launch_bounds__(256, 4)
void pass_hi(const float* __restrict__ src, int srcf32, uint2* __restrict__ dst,
             const float2* __restrict__ cs, int layer, int do_wrap, int do_chain) {
  __shared__ float4 lds4[LDSN];
  phase_hi((const void*)src, srcf32, dst, cs + layer * 20,
           blockIdx.x & 7, blockIdx.x >> 3, do_wrap, do_chain, lds4);
}

__global__ __launch_bounds__(256, 4)
void pass_lo(const uint2* __restrict__ src, uint2* __restrict__ dst,
             const float2* __restrict__ cs, int layer, int do_chain, int do_meas,
             float* __restrict__ outp) {
  __shared__ float4 lds4[LDSN];
  phase_lo(src, dst, cs + layer * 20, blockIdx.x & 7, blockIdx.x >> 3,
           do_chain, do_meas, outp, lds4);
}

extern "C" void kernel_launch(void* const* d_in, const int* in_sizes, int n_in,
                              void* d_out, int out_size, void* d_ws, size_t ws_size,
                              hipStream_t stream) {
  const float* x = (const float*)d_in[0];
  const float* theta = (const float*)d_in[1];
  float* outp = (float*)d_out;
  int* bar = (int*)d_ws;
  float2* cs = (float2*)((char*)d_ws + 12288);
  uint2* state = (uint2*)((char*)d_ws + 16384);  // fp16 state: 16 MB

  (void)hipMemsetAsync(d_out, 0, 64 * sizeof(float), stream);
  (void)hipMemsetAsync(d_ws, 0, 16384, stream);

  const float* xa = x; const float* ta = theta; uint2* sa = state; float* oa = outp; int* ba = bar;
  void* ka[5] = {(void*)&xa, (void*)&ta, (void*)&sa, (void*)&oa, (void*)&ba};
  hipError_t e = hipLaunchCooperativeKernel((void*)qae_mega, dim3(1024), dim3(256), ka, 0, stream);
  if (e != hipSuccess) {
    prep_angles<<<1, 512, 0, stream>>>(theta, cs);
    for (int L = 0; L < 13; ++L) {
      pass_hi<<<1024, 256, 0, stream>>>((L == 0) ? x : (const float*)state, (L == 0) ? 1 : 0,
                                        state, cs, L, (L >= 1) ? 1 : 0, (L < 12) ? 1 : 0);
      pass_lo<<<1024, 256, 0, stream>>>(state, state, cs, L,
                                        (L < 12) ? 1 : 0, (L == 12) ? 1 : 0, outp);
    }
  }
}

// Round 7
// 563.309 us; speedup vs baseline: 1.5847x; 1.5847x over previous
//
#include <hip/hip_runtime.h>
#include <hip/hip_fp16.h>

typedef unsigned int u32;

// 20-qubit state-vector sim, batch 8. Inter-pass state FP16 (16 MB total, 2 MB per
// XCD slice -> resident in the 4 MB per-XCD L2); gate math fp32.
// qubit q <-> bit (19-q). RY: new0 = c*a + s*b ; new1 = c*b - s*a.
// Chain per layer (bits): (19->18)...(1->0),(0->19) (wrap deferred to next hi phase).
// Hi phase: resident {19..11}u{3..0}, tile m = b10..b4. Lo phase: resident {12..0},
// tile m = b19..b13. ONE cooperative kernel, 1024 blocks (4/CU), 26 phases.
//
// Round-7 sync design:
//  * Startup (NO RMW): block publishes (xcd+1) to its own slot; wave0 polls all 1024
//    slots, then computes rank = #{blk' < blk with same xcd}, cnt = slice size, and
//    pres = OR of xcd bitmask. pres==0xFF -> fast mode (slice = physical XCD).
//  * Hot barriers (NO RMW): arrive = relaxed agent store of phase u into own slice
//    slot; wait = wave0 polls the slice's cnt slots until min >= u; then buffer_inv
//    (vL1 invalidate). State stores are already in local L2 at arrival (vmcnt(0)
//    inside __syncthreads) -> same-XCD visibility without any L2 flush.
//  * Fallback (some XCD unrepresented): same schedule, blk-derived tiles, global
//    flag barrier with agent release/acquire fences (correct under any mapping).

#define LDSN 2048  // float4 entries = 32 KB

__device__ __forceinline__ int swzH(int l) { return l ^ (((l >> 5) & 1) << 2); }
__device__ __forceinline__ int swzL(int l) { return l ^ ((l >> 3) & 7); }

__device__ __forceinline__ void h4_to_f(uint2 q, float* d) {
  float2 a = __half22float2(*(__half2*)&q.x);
  float2 b = __half22float2(*(__half2*)&q.y);
  d[0] = a.x; d[1] = a.y; d[2] = b.x; d[3] = b.y;
}
__device__ __forceinline__ uint2 f4_to_h(const float* s) {
  __half2 a = __float22half2_rn(make_float2(s[0], s[1]));
  __half2 b = __float22half2_rn(make_float2(s[2], s[3]));
  uint2 q; q.x = *(u32*)&a; q.y = *(u32*)&b; return q;
}

template<int K>
__device__ __forceinline__ void ry32(float* v, float c, float s) {
#pragma unroll
  for (int i = 0; i < 32; ++i)
    if (!(i & (1 << K))) {
      float a = v[i], b = v[i | (1 << K)];
      v[i] = c * a + s * b;
      v[i | (1 << K)] = c * b - s * a;
    }
}
template<int J, int K>
__device__ __forceinline__ void cnot_rr32(float* v) {
#pragma unroll
  for (int i = 0; i < 32; ++i)
    if ((i & (1 << J)) && !(i & (1 << K))) {
      float tmp = v[i]; v[i] = v[i | (1 << K)]; v[i | (1 << K)] = tmp;
    }
}
template<int K>
__device__ __forceinline__ void cnot_tr32(float* v, int cond) {
#pragma unroll
  for (int i = 0; i < 32; ++i)
    if (!(i & (1 << K))) {
      float a = v[i], b = v[i | (1 << K)];
      v[i] = cond ? b : a;
      v[i | (1 << K)] = cond ? a : b;
    }
}

// ---------------- Hi phase body ----------------
// R1: reg {19,18,17,1,0}; thread t7..t2 = b16..b11, t1t0 = b3b2
// R2: reg {16,15,14,1,0}; thread t7..t5 = b19..b17, t4..t2 = b13..b11, t1t0 = b3b2
// R3: reg {13,12,11,1,0}; thread t7..t2 = b19..b14, t1t0 = b3b2
__device__ __forceinline__ void phase_hi(const void* __restrict__ src, int srcf32,
                                         uint2* __restrict__ dst, const float2* csl,
                                         int s, int m, int do_wrap, int do_chain, float4* lds4) {
  const int t = threadIdx.x;
  const size_t sbase = ((size_t)s << 18) | ((size_t)m << 2);
  float v[32];

  if (srcf32) {
    const float4* s4 = (const float4*)src;
#pragma unroll
    for (int rq = 0; rq < 8; ++rq) {
      size_t g4 = sbase | ((size_t)rq << 15) | ((size_t)(t >> 2) << 9) | (size_t)(t & 3);
      float4 x = s4[g4];
      v[4*rq] = x.x; v[4*rq+1] = x.y; v[4*rq+2] = x.z; v[4*rq+3] = x.w;
    }
  } else {
    const uint2* sh = (const uint2*)src;
#pragma unroll
    for (int rq = 0; rq < 8; ++rq) {
      size_t g4 = sbase | ((size_t)rq << 15) | ((size_t)(t >> 2) << 9) | (size_t)(t & 3);
      h4_to_f(sh[g4], &v[4*rq]);
    }
  }
  if (do_wrap) cnot_rr32<0, 4>(v);                 // wrap (0->19) of previous layer
  { float2 a = csl[0]; ry32<4>(v, a.x, a.y); }     // q0  b19
  { float2 a = csl[1]; ry32<3>(v, a.x, a.y); }     // q1  b18
  { float2 a = csl[2]; ry32<2>(v, a.x, a.y); }     // q2  b17
  if (do_chain) { cnot_rr32<4, 3>(v); cnot_rr32<3, 2>(v); }  // (19->18),(18->17)
#pragma unroll
  for (int rq = 0; rq < 8; ++rq)
    lds4[swzH((rq << 8) | t)] = make_float4(v[4*rq], v[4*rq+1], v[4*rq+2], v[4*rq+3]);
  __syncthreads();
#pragma unroll
  for (int rq = 0; rq < 8; ++rq) {
    int l = ((t >> 5) << 8) | (rq << 5) | (((t >> 2) & 7) << 2) | (t & 3);
    float4 x = lds4[swzH(l)];
    v[4*rq] = x.x; v[4*rq+1] = x.y; v[4*rq+2] = x.z; v[4*rq+3] = x.w;
  }
  { float2 a = csl[3]; ry32<4>(v, a.x, a.y); }     // q3  b16
  { float2 a = csl[4]; ry32<3>(v, a.x, a.y); }     // q4  b15
  { float2 a = csl[5]; ry32<2>(v, a.x, a.y); }     // q5  b14
  if (do_chain) {
    cnot_tr32<4>(v, (t >> 5) & 1);                 // (17->16), ctrl b17 = t5
    cnot_rr32<4, 3>(v);                            // (16->15)
    cnot_rr32<3, 2>(v);                            // (15->14)
  }
#pragma unroll
  for (int rq = 0; rq < 8; ++rq) {
    int l = ((t >> 5) << 8) | (rq << 5) | (((t >> 2) & 7) << 2) | (t & 3);
    lds4[swzH(l)] = make_float4(v[4*rq], v[4*rq+1], v[4*rq+2], v[4*rq+3]);
  }
  __syncthreads();
#pragma unroll
  for (int rq = 0; rq < 8; ++rq) {
    int l = ((t >> 2) << 5) | (rq << 2) | (t & 3);
    float4 x = lds4[swzH(l)];
    v[4*rq] = x.x; v[4*rq+1] = x.y; v[4*rq+2] = x.z; v[4*rq+3] = x.w;
  }
  { float2 a = csl[6]; ry32<4>(v, a.x, a.y); }     // q6  b13
  { float2 a = csl[7]; ry32<3>(v, a.x, a.y); }     // q7  b12
  { float2 a = csl[8]; ry32<2>(v, a.x, a.y); }     // q8  b11
  if (do_chain) {
    cnot_tr32<4>(v, (t >> 2) & 1);                 // (14->13), ctrl b14 = t2
    cnot_rr32<4, 3>(v);                            // (13->12)
    cnot_rr32<3, 2>(v);                            // (12->11)
  }
#pragma unroll
  for (int rq = 0; rq < 8; ++rq) {
    size_t g4 = sbase | ((size_t)(t >> 2) << 12) | ((size_t)rq << 9) | (size_t)(t & 3);
    dst[g4] = f4_to_h(&v[4*rq]);
  }
}

// ---------------- Lo phase body ----------------
// R1: reg {10,9,8,1,0};  thread t7t6 = b12b11, t5..t0 = b7..b2
// R2: reg {7,6,5,1,0};   thread t7..t3 = b12..b8, t2..t0 = b4..b2
// R3: reg {4,3,2,1,0};   thread t7..t0 = b12..b5
__device__ __forceinline__ void phase_lo(const uint2* __restrict__ src, uint2* __restrict__ dst,
                                         const float2* csl, int s, int m,
                                         int do_chain, int do_meas, float* outp, float4* lds4) {
  const int t = threadIdx.x;
  const size_t base4 = ((size_t)s << 18) | ((size_t)m << 11);
  float v[32];

#pragma unroll
  for (int rq = 0; rq < 8; ++rq) {
    int l = ((t >> 6) << 9) | (rq << 6) | (t & 63);
    h4_to_f(src[base4 + l], &v[4*rq]);
  }
  { float2 a = csl[9];  ry32<4>(v, a.x, a.y); }    // q9  b10
  { float2 a = csl[10]; ry32<3>(v, a.x, a.y); }    // q10 b9
  { float2 a = csl[11]; ry32<2>(v, a.x, a.y); }    // q11 b8
  if (do_chain) {
    cnot_tr32<4>(v, (t >> 6) & 1);                 // (11->10), ctrl b11 = t6
    cnot_rr32<4, 3>(v);                            // (10->9)
    cnot_rr32<3, 2>(v);                            // (9->8)
  }
#pragma unroll
  for (int rq = 0; rq < 8; ++rq) {
    int l = ((t >> 6) << 9) | (rq << 6) | (t & 63);
    lds4[swzL(l)] = make_float4(v[4*rq], v[4*rq+1], v[4*rq+2], v[4*rq+3]);
  }
  __syncthreads();
#pragma unroll
  for (int rq = 0; rq < 8; ++rq) {
    int l = ((t >> 3) << 6) | (rq << 3) | (t & 7);
    float4 x = lds4[swzL(l)];
    v[4*rq] = x.x; v[4*rq+1] = x.y; v[4*rq+2] = x.z; v[4*rq+3] = x.w;
  }
  { float2 a = csl[12]; ry32<4>(v, a.x, a.y); }    // q12 b7
  { float2 a = csl[13]; ry32<3>(v, a.x, a.y); }    // q13 b6
  { float2 a = csl[14]; ry32<2>(v, a.x, a.y); }    // q14 b5
  if (do_chain) {
    cnot_tr32<4>(v, (t >> 3) & 1);                 // (8->7), ctrl b8 = t3
    cnot_rr32<4, 3>(v);                            // (7->6)
    cnot_rr32<3, 2>(v);                            // (6->5)
  }
#pragma unroll
  for (int rq = 0; rq < 8; ++rq) {
    int l = ((t >> 3) << 6) | (rq << 3) | (t & 7);
    lds4[swzL(l)] = make_float4(v[4*rq], v[4*rq+1], v[4*rq+2], v[4*rq+3]);
  }
  __syncthreads();
#pragma unroll
  for (int rq = 0; rq < 8; ++rq) {
    int l = (t << 3) | rq;
    float4 x = lds4[swzL(l)];
    v[4*rq] = x.x; v[4*rq+1] = x.y; v[4*rq+2] = x.z; v[4*rq+3] = x.w;
  }
  { float2 a = csl[15]; ry32<4>(v, a.x, a.y); }    // q15 b4
  { float2 a = csl[16]; ry32<3>(v, a.x, a.y); }    // q16 b3
  { float2 a = csl[17]; ry32<2>(v, a.x, a.y); }    // q17 b2
  { float2 a = csl[18]; ry32<1>(v, a.x, a.y); }    // q18 b1
  { float2 a = csl[19]; ry32<0>(v, a.x, a.y); }    // q19 b0
  if (do_chain) {
    cnot_tr32<4>(v, t & 1);                        // (5->4), ctrl b5 = t0
    cnot_rr32<4, 3>(v);                            // (4->3)
    cnot_rr32<3, 2>(v);                            // (3->2)
    cnot_rr32<2, 1>(v);                            // (2->1)
    cnot_rr32<1, 0>(v);                            // (1->0)
  }

  if (!do_meas) {
#pragma unroll
    for (int rq = 0; rq < 8; ++rq) {
      int l = (t << 3) | rq;
      lds4[swzL(l)] = make_float4(v[4*rq], v[4*rq+1], v[4*rq+2], v[4*rq+3]);
    }
    __syncthreads();
#pragma unroll
    for (int rq = 0; rq < 8; ++rq) {
      int l = ((t >> 6) << 9) | (rq << 6) | (t & 63);
      float4 x = lds4[swzL(l)];
      dst[base4 + l] = f4_to_h((float*)&x);
    }
  } else {
    float p[8];
#pragma unroll
    for (int b = 0; b < 8; ++b) p[b] = 0.f;
#pragma unroll
    for (int rq = 0; rq < 8; ++rq)
#pragma unroll
      for (int j = 0; j < 4; ++j) {
        float a = v[4*rq + j];
        p[((rq & 1) << 2) | j] += a * a;
      }
#pragma unroll
    for (int b = 0; b < 8; ++b) {
      p[b] += __shfl_xor(p[b], 32);
      p[b] += __shfl_xor(p[b], 16);
      p[b] += __shfl_xor(p[b], 8);
      p[b] += __shfl_xor(p[b], 4);
      p[b] += __shfl_xor(p[b], 2);
      p[b] += __shfl_xor(p[b], 1);
    }
    __syncthreads();
    float* red = (float*)lds4;
    if ((t & 63) == 0) {
#pragma unroll
      for (int b = 0; b < 8; ++b) red[(t >> 6) * 8 + b] = p[b];
    }
    __syncthreads();
    if (t < 8) {
      float sum = red[t] + red[8 + t] + red[16 + t] + red[24 + t];
      atomicAdd(outp + s * 8 + t, sum);
    }
  }
}

// ---------------- flag barrier (no RMW anywhere) ----------------
// Arrive: relaxed agent store of monotonic phase u into own slot (rank).
// Wait: wave0 polls cnt slots until min >= u.
// weak: state stores are in local L2 at arrival (vmcnt0 in __syncthreads);
//       vL1 buffer_inv after -> same-XCD correctness, no L2 flush.
// strong: agent release/acquire fences -> correct under any block->XCD mapping.
__device__ __forceinline__ void barx(int* fbase, int rank, int cnt, int u, bool strong) {
  __syncthreads();
  if (strong) __builtin_amdgcn_fence(__ATOMIC_RELEASE, "agent");
  if (threadIdx.x == 0)
    __hip_atomic_store(fbase + rank, u, __ATOMIC_RELAXED, __HIP_MEMORY_SCOPE_AGENT);
  if (threadIdx.x < 64) {
    for (;;) {
      int mn = 0x7fffffff;
#pragma unroll 1
      for (int j = threadIdx.x; j < cnt; j += 64) {
        int vv = __hip_atomic_load(fbase + j, __ATOMIC_RELAXED, __HIP_MEMORY_SCOPE_AGENT);
        mn = (vv < mn) ? vv : mn;
      }
      if (__all(mn >= u)) break;
      __builtin_amdgcn_s_sleep(4);
    }
  }
  __syncthreads();
  if (strong) __builtin_amdgcn_fence(__ATOMIC_ACQUIRE, "agent");
  else asm volatile("buffer_inv" ::: "memory");  // invalidate this CU's vL1
}

// bar layout (ints): [0..1023] startup slots (xcd+1 per block);
// [2048 + s*1024 + r] fast phase flags (8 slices x 1024);
// [10240 + blk] strong-mode global phase flags.  All zeroed pre-launch.
__global__ __launch_bounds__(256, 4)
void qae_mega(const float* __restrict__ x, const float* __restrict__ theta,
              uint2* __restrict__ state, float* __restrict__ outp, int* __restrict__ bar) {
  __shared__ float4 lds4[LDSN];
  __shared__ float2 csh[260];
  __shared__ int sh_xcd, sh_rank, sh_cnt, sh_ok;
  const int t = threadIdx.x;
  const int blk = blockIdx.x;

  for (int i = t; i < 260; i += 256) {
    float h = 0.5f * theta[i];
    csh[i] = make_float2(cosf(h), sinf(h));
  }
  if (t == 0)  // HW_REG_XCC_ID: id 20, offset 0, width 32
    sh_xcd = __builtin_amdgcn_s_getreg(20 | (31 << 11)) & 7;
  __syncthreads();
  const int myxcd = sh_xcd;

  // publish own xcd (flag IS the data; no fence needed)
  if (t == 0)
    __hip_atomic_store(bar + blk, myxcd + 1, __ATOMIC_RELAXED, __HIP_MEMORY_SCOPE_AGENT);
  // wave0: poll all 1024 startup slots, then derive rank/cnt/presence
  if (t < 64) {
    int v[16];
    for (;;) {
      int mn = 0x7fffffff;
#pragma unroll
      for (int j = 0; j < 16; ++j) {
        v[j] = __hip_atomic_load(bar + t * 16 + j, __ATOMIC_RELAXED, __HIP_MEMORY_SCOPE_AGENT);
        mn = (v[j] < mn) ? v[j] : mn;
      }
      if (__all(mn >= 1)) break;
      __builtin_amdgcn_s_sleep(8);
    }
    int rank = 0, cnt = 0, pres = 0;
#pragma unroll
    for (int j = 0; j < 16; ++j) {
      int xv = v[j] - 1;
      pres |= (1 << xv);
      if (xv == myxcd) {
        cnt++;
        if ((t * 16 + j) < blk) rank++;
      }
    }
#pragma unroll
    for (int off = 32; off >= 1; off >>= 1) {
      rank += __shfl_xor(rank, off);
      cnt  += __shfl_xor(cnt, off);
      pres |= __shfl_xor(pres, off);
    }
    if (t == 0) { sh_rank = rank; sh_cnt = cnt; sh_ok = (pres == 255); }
  }
  __syncthreads();

  const bool strong = (sh_ok == 0);
  const int s      = strong ? (blk & 7)  : myxcd;
  const int rank   = strong ? blk        : sh_rank;
  const int cnt    = strong ? 1024       : sh_cnt;
  const int m0     = strong ? (blk >> 3) : sh_rank;
  const int mstrd  = strong ? 128        : sh_cnt;
  int* fbase = strong ? (bar + 10240) : (bar + 2048 + (s << 10));
  int u = 0;

#pragma unroll 1
  for (int L = 0; L < 13; ++L) {
#pragma unroll 1
    for (int m = m0; m < 128; m += mstrd)
      phase_hi((L == 0) ? (const void*)x : (const void*)state, (L == 0) ? 1 : 0,
               state, csh + L * 20, s, m, (L >= 1) ? 1 : 0, (L < 12) ? 1 : 0, lds4);
    barx(fbase, rank, cnt, ++u, strong);
#pragma unroll 1
    for (int m = m0; m < 128; m += mstrd)
      phase_lo(state, state, csh + L * 20, s, m,
               (L < 12) ? 1 : 0, (L == 12) ? 1 : 0, outp, lds4);
    if (L < 12) barx(fbase, rank, cnt, ++u, strong);
  }
}

// ---------------- standalone fallback kernels (multi-dispatch path) ----------------
__global__ void prep_angles(const float* __restrict__ theta, float2* __restrict__ cs) {
  int i = threadIdx.x;
  if (i < 260) {
    float h = 0.5f * theta[i];
    cs[i] = make_float2(cosf(h), sinf(h));
  }
}

__global__ __launch_bounds__(256, 4)
void pass_hi(const float* __restrict__ src, int srcf32, uint2* __restrict__ dst,
             const float2* __restrict__ cs, int layer, int do_wrap, int do_chain) {
  __shared__ float4 lds4[LDSN];
  phase_hi((const void*)src, srcf32, dst, cs + layer * 20,
           blockIdx.x & 7, blockIdx.x >> 3, do_wrap, do_chain, lds4);
}

__global__ __launch_bounds__(256, 4)
void pass_lo(const uint2* __restrict__ src, uint2* __restrict__ dst,
             const float2* __restrict__ cs, int layer, int do_chain, int do_meas,
             float* __restrict__ outp) {
  __shared__ float4 lds4[LDSN];
  phase_lo(src, dst, cs + layer * 20, blockIdx.x & 7, blockIdx.x >> 3,
           do_chain, do_meas, outp, lds4);
}

extern "C" void kernel_launch(void* const* d_in, const int* in_sizes, int n_in,
                              void* d_out, int out_size, void* d_ws, size_t ws_size,
                              hipStream_t stream) {
  const float* x = (const float*)d_in[0];
  const float* theta = (const float*)d_in[1];
  float* outp = (float*)d_out;
  int* bar = (int*)d_ws;
  float2* cs = (float2*)((char*)d_ws + 49152);
  uint2* state = (uint2*)((char*)d_ws + 65536);  // fp16 state: 16 MB

  (void)hipMemsetAsync(d_out, 0, 64 * sizeof(float), stream);
  (void)hipMemsetAsync(d_ws, 0, 49152, stream);

  const float* xa = x; const float* ta = theta; uint2* sa = state; float* oa = outp; int* ba = bar;
  void* ka[5] = {(void*)&xa, (void*)&ta, (void*)&sa, (void*)&oa, (void*)&ba};
  hipError_t e = hipLaunchCooperativeKernel((void*)qae_mega, dim3(1024), dim3(256), ka, 0, stream);
  if (e != hipSuccess) {
    prep_angles<<<1, 512, 0, stream>>>(theta, cs);
    for (int L = 0; L < 13; ++L) {
      pass_hi<<<1024, 256, 0, stream>>>((L == 0) ? x : (const float*)state, (L == 0) ? 1 : 0,
                                        state, cs, L, (L >= 1) ? 1 : 0, (L < 12) ? 1 : 0);
      pass_lo<<<1024, 256, 0, stream>>>(state, state, cs, L,
                                        (L < 12) ? 1 : 0, (L == 12) ? 1 : 0, outp);
    }
  }
}